// Round 6
// baseline (103.767 us; speedup 1.0000x reference)
//
#include <hip/hip_runtime.h>

#define BB 8
#define TT 128
#define DD 256
#define BT (BB * TT)       // 1024 (b,t) pairs
#define SP 32              // stripe rows
#define NS (DD / SP)       // 8 stripes
#define RS 257             // padded LDS row stride (floats): +1 kills bank aliasing
#define LOG2E 1.44269504088896340736f

// R11: M-once. colsum[q] and rowsum[p] are the column/row sums of the SAME
// matrix M[p][q] = exp(d_p * e_q); R5-R10 computed every element twice.
// Model (fits R5/R8/R9/R10): v_exp_f32 holds the SIMD issue port ~16cyc and
// phase1 ~ (16E + 2V)/SIMD, occupancy-invariant -> the only lever is E.
// Here each element is computed ONCE (E halves: 512 -> 256 exps/thread),
// streamed through a 32-row LDS stripe (scalar live state only -- R7's spill
// trap avoided), with rowsum accumulated cooperatively via ds_add_f32.
// LDS geometry: write m[p*RS+q]: bank=(p+q)%32 -> 2-way (free).
// read row rr=tid&31, chunk cc=tid>>5, b128: bank=(rr+4i+j)%32 -> 32 distinct
// rows per wave = 2-way (free). atomicAdd: 32 addrs/wave, 2-way.
__global__ __launch_bounds__(256, 4) void attn_monce_kernel(
    const float* __restrict__ dec,   // [B, D]
    const float* __restrict__ enc,   // [B, T, D]
    float* __restrict__ ws) {        // [BT, D] per-(b,t) contributions
    const int blk = blockIdx.x;              // b*TT + t
    const int b = blk >> 7;
    const int tid = threadIdx.x;             // q

    const float* __restrict__ drow = dec + b * DD;    // uniform pointer
    const float* __restrict__ erow = enc + blk * DD;  // uniform pointer

    __shared__ float m[SP * RS];     // 32.9 KB stripe of M
    __shared__ float rowacc[DD];     // rowsum accumulators

    const float ev = erow[tid];            // per-lane
    const float el2 = ev * LOG2E;          // M[p][q] = exp2(d_p * el2)

    rowacc[tid] = 0.f;                     // visible before first barrier

    const int rr = tid & 31;               // reduce: row within stripe
    const int cc = tid >> 5;               // reduce: 32-float chunk 0..7
    float* mwr = m + tid;                          // write col q, offset p*RS
    const float* mrd = m + rr * RS + cc * 32;      // read row rr, chunk cc

    float cs0 = 0.f, cs1 = 0.f, cs2 = 0.f, cs3 = 0.f;
    for (int s = 0; s < NS; ++s) {
        // compute stripe rows p = s*SP .. +SP: 1 exp per element (M-once)
        const float* dstripe = drow + s * SP;
        #pragma unroll
        for (int p4 = 0; p4 < SP; p4 += 4) {
            float4 d4 = *reinterpret_cast<const float4*>(dstripe + p4);  // s_load
            const float v0 = __builtin_amdgcn_exp2f(d4.x * el2);
            const float v1 = __builtin_amdgcn_exp2f(d4.y * el2);
            const float v2 = __builtin_amdgcn_exp2f(d4.z * el2);
            const float v3 = __builtin_amdgcn_exp2f(d4.w * el2);
            cs0 += v0; cs1 += v1; cs2 += v2; cs3 += v3;      // colsum (own q)
            mwr[(p4 + 0) * RS] = v0;   // ds_write_b32, imm offset (p4 static)
            mwr[(p4 + 1) * RS] = v1;
            mwr[(p4 + 2) * RS] = v2;
            mwr[(p4 + 3) * RS] = v3;
        }
        __syncthreads();
        // cooperative row-reduce: thread sums 32 floats of row rr
        float a0 = 0.f, a1 = 0.f, a2 = 0.f, a3 = 0.f;
        #pragma unroll
        for (int i = 0; i < 32; i += 4) {
            float4 v = *reinterpret_cast<const float4*>(mrd + i);  // ds_read_b128
            a0 += v.x; a1 += v.y; a2 += v.z; a3 += v.w;
        }
        atomicAdd(&rowacc[s * SP + rr], (a0 + a1) + (a2 + a3));    // ds_add_f32
        __syncthreads();   // atomics done + stripe safe to overwrite
    }

    const float cs = (cs0 + cs1) + (cs2 + cs3);
    const float rs = rowacc[tid];
    ws[blk * DD + tid] = ev * cs / rs;
}

// Phase 2 (proven in R8/R9): 64 blocks = (b, 32-wide q-slice); 256 threads =
// 8 t-chunks (16 t each) x 32 q. Lanes read consecutive q -> coalesced;
// ws is L2-resident (1 MB).
__global__ __launch_bounds__(256) void reduce_t_kernel(
    const float* __restrict__ ws, float* __restrict__ out) {
    __shared__ float red[8][32];
    const int b = blockIdx.x >> 3;
    const int qc = blockIdx.x & 7;
    const int qlane = threadIdx.x & 31;
    const int tc = threadIdx.x >> 5;         // 0..7
    const int q = qc * 32 + qlane;

    const float* p = ws + (b * TT + tc * 16) * DD + q;
    float a0 = 0.f, a1 = 0.f, a2 = 0.f, a3 = 0.f;
    #pragma unroll
    for (int t = 0; t < 16; t += 4) {
        a0 += p[(t + 0) * DD];
        a1 += p[(t + 1) * DD];
        a2 += p[(t + 2) * DD];
        a3 += p[(t + 3) * DD];
    }
    red[tc][qlane] = (a0 + a1) + (a2 + a3);
    __syncthreads();
    if (tc == 0) {
        float s = 0.f;
        #pragma unroll
        for (int u = 0; u < 8; ++u) s += red[u][qlane];
        out[b * DD + q] = s;
    }
}

extern "C" void kernel_launch(void* const* d_in, const int* in_sizes, int n_in,
                              void* d_out, int out_size, void* d_ws, size_t ws_size,
                              hipStream_t stream) {
    const float* dec = (const float*)d_in[0];  // [B, D] fp32
    const float* enc = (const float*)d_in[1];  // [B, T, D] fp32
    float* out = (float*)d_out;                // [B, D] fp32
    float* ws = (float*)d_ws;                  // >= BT*DD floats (1 MB)

    attn_monce_kernel<<<BT, 256, 0, stream>>>(dec, enc, ws);
    reduce_t_kernel<<<BB * 8, 256, 0, stream>>>(ws, out);
}